// Round 2
// baseline (742.905 us; speedup 1.0000x reference)
//
#include <hip/hip_runtime.h>
#include <math.h>

#define N_NODES 20000
#define M_PAD   20096   // 157 * 128
#define N_EDGES 320000
#define DIM_IN 768
#define DIM_H 512
#define NUM_GNNS 4
#define NEG_SLOPE 0.2f

#define GEMM_TILES 628        // (M_PAD/128) * (DIM_H/128) = 157*4
#define GEMM_GRID  632        // ceil to multiple of 8 for XCD swizzle

#define NODE_WAVE_BLOCKS 5000         // 20000 nodes / (4 waves per 256-thr block)
#define SLICED_GRID (NODE_WAVE_BLOCKS * 8)   // 8 column slices, slice = bid & 7

typedef __attribute__((ext_vector_type(8))) short short8;
typedef __attribute__((ext_vector_type(4))) float f32x4;

#define GPTR(p) (const __attribute__((address_space(1))) void*)(p)
#define LPTR(p) (__attribute__((address_space(3))) void*)(p)

__device__ __forceinline__ float bf2f(unsigned int lo16) {
  return __uint_as_float(lo16 << 16);
}
__device__ __forceinline__ unsigned short f2bf(float f) {
  unsigned int u = __float_as_uint(f);
  u += 0x7FFFu + ((u >> 16) & 1u);   // round-to-nearest-even
  return (unsigned short)(u >> 16);
}
__device__ __forceinline__ void unpack8(uint4 v, float* f) {
  f[0] = bf2f(v.x & 0xffffu); f[1] = bf2f(v.x >> 16);
  f[2] = bf2f(v.y & 0xffffu); f[3] = bf2f(v.y >> 16);
  f[4] = bf2f(v.z & 0xffffu); f[5] = bf2f(v.z >> 16);
  f[6] = bf2f(v.w & 0xffffu); f[7] = bf2f(v.w >> 16);
}
__device__ __forceinline__ uint4 pack8(const float* o) {
  uint4 pv;
  pv.x = (unsigned)f2bf(o[0]) | ((unsigned)f2bf(o[1]) << 16);
  pv.y = (unsigned)f2bf(o[2]) | ((unsigned)f2bf(o[3]) << 16);
  pv.z = (unsigned)f2bf(o[4]) | ((unsigned)f2bf(o[5]) << 16);
  pv.w = (unsigned)f2bf(o[6]) | ((unsigned)f2bf(o[7]) << 16);
  return pv;
}

__device__ __forceinline__ float waveReduceSum(float v) {
#pragma unroll
  for (int off = 32; off > 0; off >>= 1) v += __shfl_xor(v, off, 64);
  return v;
}
__device__ __forceinline__ float waveReduceMax(float v) {
#pragma unroll
  for (int off = 32; off > 0; off >>= 1) v = fmaxf(v, __shfl_xor(v, off, 64));
  return v;
}

// ================= MFMA GEMM (lean, R5 epilogue) + XCD tile swizzle =================
// Cbf[M_PAD,512](bf16) = A[M_PAD,K](bf16) @ Bt[512,K]^T (+bias)
__global__ __launch_bounds__(256) void gemm_mfma_bf16(
    const unsigned short* __restrict__ A,
    const unsigned short* __restrict__ Bt,
    const float* __restrict__ bias,
    unsigned short* __restrict__ Cbf,
    int K) {
  int bid = blockIdx.x;
  int tile = (bid & 7) * (GEMM_GRID / 8) + (bid >> 3);
  if (tile >= GEMM_TILES) return;
  int brow = tile >> 2;   // 0..156
  int bcol = tile & 3;    // 0..3

  __shared__ __align__(16) unsigned short As[128 * 32];
  __shared__ __align__(16) unsigned short Bs[128 * 32];
  int tid = threadIdx.x;
  int wave = tid >> 6, lane = tid & 63;
  int wm = wave >> 1, wn = wave & 1;

  int rl = lane >> 2;
  int kc = (lane & 3) ^ ((lane >> 3) & 3);
  int r0 = 32 * wave;
  const unsigned short* gA0 = A + (size_t)(brow * 128 + r0 + rl) * K + kc * 8;
  const unsigned short* gA1 = gA0 + (size_t)16 * K;
  const unsigned short* gB0 = Bt + (size_t)(bcol * 128 + r0 + rl) * K + kc * 8;
  const unsigned short* gB1 = gB0 + (size_t)16 * K;
  unsigned short* lA0 = As + r0 * 32;
  unsigned short* lA1 = As + (r0 + 16) * 32;
  unsigned short* lB0 = Bs + r0 * 32;
  unsigned short* lB1 = Bs + (r0 + 16) * 32;

  int mrow = lane & 15;
  int q = lane >> 4;
  int swz = (q ^ ((mrow >> 1) & 3)) * 8;
  const short8* ra = (const short8*)(As + (64 * wm + mrow) * 32 + swz);
  const short8* rb = (const short8*)(Bs + (64 * wn + mrow) * 32 + swz);

  f32x4 acc[4][4];
#pragma unroll
  for (int i = 0; i < 4; ++i)
#pragma unroll
    for (int j = 0; j < 4; ++j) acc[i][j] = (f32x4)(0.f);

  for (int k0 = 0; k0 < K; k0 += 32) {
    __syncthreads();
    __builtin_amdgcn_global_load_lds(GPTR(gA0 + k0), LPTR(lA0), 16, 0, 0);
    __builtin_amdgcn_global_load_lds(GPTR(gA1 + k0), LPTR(lA1), 16, 0, 0);
    __builtin_amdgcn_global_load_lds(GPTR(gB0 + k0), LPTR(lB0), 16, 0, 0);
    __builtin_amdgcn_global_load_lds(GPTR(gB1 + k0), LPTR(lB1), 16, 0, 0);
    __syncthreads();
    short8 a[4], b[4];
#pragma unroll
    for (int t = 0; t < 4; ++t) a[t] = ra[t * 64];
#pragma unroll
    for (int t = 0; t < 4; ++t) b[t] = rb[t * 64];
#pragma unroll
    for (int mt = 0; mt < 4; ++mt)
#pragma unroll
      for (int nt = 0; nt < 4; ++nt)
        acc[mt][nt] = __builtin_amdgcn_mfma_f32_16x16x32_bf16(a[mt], b[nt], acc[mt][nt], 0, 0, 0);
  }

  int colb = bcol * 128 + 64 * wn + (lane & 15);
  int rowb = brow * 128 + 64 * wm + 4 * q;
#pragma unroll
  for (int nt = 0; nt < 4; ++nt) {
    int col = colb + 16 * nt;
    float bv = bias ? bias[col] : 0.f;
#pragma unroll
    for (int mt = 0; mt < 4; ++mt) {
      int row = rowb + 16 * mt;
#pragma unroll
      for (int i = 0; i < 4; ++i)
        Cbf[(size_t)(row + i) * DIM_H + col] = f2bf(acc[mt][nt][i] + bv);
    }
  }
}

// ================= conversions =================
__global__ void convert_feat(const float* __restrict__ feat, unsigned short* __restrict__ Abf) {
  int t = blockIdx.x * blockDim.x + threadIdx.x;
  const int CHUNKS = M_PAD * DIM_IN / 8;
  if (t >= CHUNKS) return;
  int row = t / (DIM_IN / 8);
  uint4 o;
  if (row < N_NODES) {
    const float4* p = (const float4*)(feat + (size_t)t * 8);
    float4 x = p[0], y = p[1];
    o.x = (unsigned)f2bf(x.x) | ((unsigned)f2bf(x.y) << 16);
    o.y = (unsigned)f2bf(x.z) | ((unsigned)f2bf(x.w) << 16);
    o.z = (unsigned)f2bf(y.x) | ((unsigned)f2bf(y.y) << 16);
    o.w = (unsigned)f2bf(y.z) | ((unsigned)f2bf(y.w) << 16);
  } else {
    o = make_uint4(0, 0, 0, 0);
  }
  ((uint4*)Abf)[t] = o;
}

// LDS-tiled transpose: in [R,C] f32 -> out [C,R] bf16. R,C multiples of 32.
__global__ __launch_bounds__(256) void transpose_bf16(const float* __restrict__ in,
                                                      unsigned short* __restrict__ out,
                                                      int R, int C) {
  __shared__ float tile[32][33];
  int tx = threadIdx.x, ty = threadIdx.y;
  size_t base = (size_t)blockIdx.z * R * C;
  int r0 = blockIdx.x * 32, c0 = blockIdx.y * 32;
#pragma unroll
  for (int i = 0; i < 4; ++i) {
    int r = r0 + ty + i * 8;
    tile[ty + i * 8][tx] = in[base + (size_t)r * C + c0 + tx];
  }
  __syncthreads();
#pragma unroll
  for (int i = 0; i < 4; ++i) {
    int c = c0 + ty + i * 8;
    out[base + (size_t)c * R + r0 + tx] = f2bf(tile[tx][ty + i * 8]);
  }
}

// ================= CSR build (dst -> src adjacency) =================
__global__ void count_edges(const int* __restrict__ dst, int* __restrict__ counts) {
  int k = blockIdx.x * blockDim.x + threadIdx.x;
  if (k < N_EDGES) atomicAdd(&counts[dst[k]], 1);
}

__global__ __launch_bounds__(1024) void scan_kernel(const int* __restrict__ counts,
                                                    int* __restrict__ indptr) {
  __shared__ int part[1024];
  int tid = threadIdx.x;
  const int CH = (N_NODES + 1023) / 1024;
  int base = tid * CH;
  int s = 0;
  for (int i = 0; i < CH; ++i) {
    int idx = base + i;
    if (idx < N_NODES) s += counts[idx];
  }
  part[tid] = s;
  __syncthreads();
  for (int off = 1; off < 1024; off <<= 1) {
    int v = (tid >= off) ? part[tid - off] : 0;
    __syncthreads();
    part[tid] += v;
    __syncthreads();
  }
  int run = (tid == 0) ? 0 : part[tid - 1];
  for (int i = 0; i < CH; ++i) {
    int idx = base + i;
    if (idx < N_NODES) {
      indptr[idx] = run;
      run += counts[idx];
      if (idx == N_NODES - 1) indptr[N_NODES] = run;
    }
  }
}

__global__ void fill_adj(const int* __restrict__ src, const int* __restrict__ dst,
                         const int* __restrict__ indptr, int* __restrict__ cursor,
                         int* __restrict__ adjsrc) {
  int k = blockIdx.x * blockDim.x + threadIdx.x;
  if (k < N_EDGES) {
    int d = dst[k];
    int pos = atomicAdd(&cursor[d], 1);
    adjsrc[indptr[d] + pos] = src[k];
  }
}

// ================= el/er from bf16 z =================
__global__ __launch_bounds__(256) void eler_bf(const unsigned short* __restrict__ zbf,
                                               const float* __restrict__ al,
                                               const float* __restrict__ ar,
                                               float* __restrict__ el, float* __restrict__ er) {
  int wid = (blockIdx.x * blockDim.x + threadIdx.x) >> 6;
  int lane = threadIdx.x & 63;
  if (wid >= N_NODES) return;
  uint4 zv = ((const uint4*)(zbf + (size_t)wid * DIM_H))[lane];
  float z[8];
  unpack8(zv, z);
  const float4* al4 = (const float4*)(al + lane * 8);
  const float4* ar4 = (const float4*)(ar + lane * 8);
  float4 a0 = al4[0], a1 = al4[1], r0 = ar4[0], r1 = ar4[1];
  float sl = z[0] * a0.x + z[1] * a0.y + z[2] * a0.z + z[3] * a0.w +
             z[4] * a1.x + z[5] * a1.y + z[6] * a1.z + z[7] * a1.w;
  float sr = z[0] * r0.x + z[1] * r0.y + z[2] * r0.z + z[3] * r0.w +
             z[4] * r1.x + z[5] * r1.y + z[6] * r1.z + z[7] * r1.w;
  sl = waveReduceSum(sl);
  sr = waveReduceSum(sr);
  if (lane == 0) { el[wid] = sl; er[wid] = sr; }
}

// ================= edge softmax -> per-edge alpha (el/er are L2-resident, cheap) ========
__global__ __launch_bounds__(256) void edge_softmax_alpha(
    const float* __restrict__ el, const float* __restrict__ er,
    const int* __restrict__ indptr, const int* __restrict__ adjsrc,
    float* __restrict__ alpha) {
  int v = (blockIdx.x * blockDim.x + threadIdx.x) >> 6;
  int lane = threadIdx.x & 63;
  if (v >= N_NODES) return;
  int begin = indptr[v], end = indptr[v + 1];
  float er_v = er[v];

  float m = -INFINITY;
  for (int j = begin + lane; j < end; j += 64) {
    float e = el[adjsrc[j]] + er_v;
    e = (e >= 0.f) ? e : NEG_SLOPE * e;
    m = fmaxf(m, e);
  }
  m = waveReduceMax(m);

  float ss = 0.f;
  for (int j = begin + lane; j < end; j += 64) {
    float e = el[adjsrc[j]] + er_v;
    e = (e >= 0.f) ? e : NEG_SLOPE * e;
    ss += __expf(e - m);
  }
  float denom = waveReduceSum(ss);
  float inv = (end > begin) ? 1.f / denom : 0.f;

  for (int j = begin + lane; j < end; j += 64) {
    float e = el[adjsrc[j]] + er_v;
    e = (e >= 0.f) ? e : NEG_SLOPE * e;
    alpha[j] = __expf(e - m) * inv;
  }
}

// ========== XCD-sliced weighted aggregate ==========
// slice = bid&7 (one XCD per slice under round-robin dispatch): each XCD gathers
// only a 20000 x 64col x 2B = 2.56 MB slice of z -> fits its private 4 MiB L2.
// Lane layout: 4 edge-slots x 16 col-lanes x 8B (one 128B line per gathered row).
__global__ __launch_bounds__(256) void gat_aggregate_sliced(
    const unsigned short* __restrict__ zbf, const float* __restrict__ alpha,
    const int* __restrict__ indptr, const int* __restrict__ adjsrc,
    const float* __restrict__ bias, unsigned short* __restrict__ out_bf) {
  int slice = blockIdx.x & 7;
  int group = blockIdx.x >> 3;
  int wave = threadIdx.x >> 6, lane = threadIdx.x & 63;
  int v = group * 4 + wave;
  if (v >= N_NODES) return;
  int slot = lane >> 4, sub = lane & 15;
  int col = slice * 64 + sub * 4;
  const unsigned short* zc = zbf + col;

  int begin = indptr[v], end = indptr[v + 1];
  float acc[4] = {0.f, 0.f, 0.f, 0.f};

  for (int c = begin; c < end; c += 64) {
    int cc = min(64, end - c);
    bool has = (c + lane < end);
    int idx = has ? adjsrc[c + lane] : 0;
    float wv = has ? alpha[c + lane] : 0.f;
    int t = 0;
    for (; (t + 2) * 4 <= cc; t += 2) {   // 2 rows in flight per slot
      int e0 = t * 4 + slot, e1 = e0 + 4;
      int s0 = __shfl(idx, e0, 64), s1 = __shfl(idx, e1, 64);
      float w0 = __shfl(wv, e0, 64), w1 = __shfl(wv, e1, 64);
      uint2 z0 = *(const uint2*)(zc + (size_t)s0 * DIM_H);
      uint2 z1 = *(const uint2*)(zc + (size_t)s1 * DIM_H);
      acc[0] += w0 * bf2f(z0.x & 0xffffu) + w1 * bf2f(z1.x & 0xffffu);
      acc[1] += w0 * bf2f(z0.x >> 16)     + w1 * bf2f(z1.x >> 16);
      acc[2] += w0 * bf2f(z0.y & 0xffffu) + w1 * bf2f(z1.y & 0xffffu);
      acc[3] += w0 * bf2f(z0.y >> 16)     + w1 * bf2f(z1.y >> 16);
    }
    for (; t * 4 < cc; ++t) {
      int e0 = t * 4 + slot;
      int s0 = __shfl(idx, e0, 64);
      float w0 = __shfl(wv, e0, 64);     // 0 for invalid slots
      uint2 z0 = *(const uint2*)(zc + (size_t)s0 * DIM_H);
      acc[0] += w0 * bf2f(z0.x & 0xffffu);
      acc[1] += w0 * bf2f(z0.x >> 16);
      acc[2] += w0 * bf2f(z0.y & 0xffffu);
      acc[3] += w0 * bf2f(z0.y >> 16);
    }
  }
#pragma unroll
  for (int i = 0; i < 4; ++i) {
    acc[i] += __shfl_xor(acc[i], 16, 64);
    acc[i] += __shfl_xor(acc[i], 32, 64);
  }
  if (slot == 0) {
    float4 bv = *(const float4*)(bias + col);
    unsigned long long pv =
        (unsigned long long)((unsigned)f2bf(acc[0] + bv.x) | ((unsigned)f2bf(acc[1] + bv.y) << 16)) |
        ((unsigned long long)((unsigned)f2bf(acc[2] + bv.z) | ((unsigned)f2bf(acc[3] + bv.w) << 16)) << 32);
    // nontemporal: don't evict the L2-resident gather slice with output lines
    __builtin_nontemporal_store(pv, (unsigned long long*)(out_bf + (size_t)v * DIM_H + col));
  }
}

// ========== XCD-sliced A_hat hop (out = z[v] + sum_{src} z[src]) ==========
__global__ __launch_bounds__(256) void propagate_sliced(
    const unsigned short* __restrict__ zin, const int* __restrict__ indptr,
    const int* __restrict__ adjsrc, unsigned short* __restrict__ out_bf,
    float* __restrict__ out_f32) {
  int slice = blockIdx.x & 7;
  int group = blockIdx.x >> 3;
  int wave = threadIdx.x >> 6, lane = threadIdx.x & 63;
  int v = group * 4 + wave;
  if (v >= N_NODES) return;
  int slot = lane >> 4, sub = lane & 15;
  int col = slice * 64 + sub * 4;
  const unsigned short* zc = zin + col;

  int begin = indptr[v], end = indptr[v + 1];
  float acc[4] = {0.f, 0.f, 0.f, 0.f};
  if (slot == 0) {  // self row (A_hat = A + I)
    uint2 sv = *(const uint2*)(zc + (size_t)v * DIM_H);
    acc[0] = bf2f(sv.x & 0xffffu); acc[1] = bf2f(sv.x >> 16);
    acc[2] = bf2f(sv.y & 0xffffu); acc[3] = bf2f(sv.y >> 16);
  }

  for (int c = begin; c < end; c += 64) {
    int cc = min(64, end - c);
    int idx = (c + lane < end) ? adjsrc[c + lane] : 0;
    int t = 0;
    for (; (t + 2) * 4 <= cc; t += 2) {
      int e0 = t * 4 + slot, e1 = e0 + 4;
      int s0 = __shfl(idx, e0, 64), s1 = __shfl(idx, e1, 64);
      uint2 z0 = *(const uint2*)(zc + (size_t)s0 * DIM_H);
      uint2 z1 = *(const uint2*)(zc + (size_t)s1 * DIM_H);
      acc[0] += bf2f(z0.x & 0xffffu) + bf2f(z1.x & 0xffffu);
      acc[1] += bf2f(z0.x >> 16)     + bf2f(z1.x >> 16);
      acc[2] += bf2f(z0.y & 0xffffu) + bf2f(z1.y & 0xffffu);
      acc[3] += bf2f(z0.y >> 16)     + bf2f(z1.y >> 16);
    }
    for (; t * 4 < cc; ++t) {
      int e0 = t * 4 + slot;
      int s0 = __shfl(idx, e0, 64);
      if (e0 < cc) {
        uint2 z0 = *(const uint2*)(zc + (size_t)s0 * DIM_H);
        acc[0] += bf2f(z0.x & 0xffffu);
        acc[1] += bf2f(z0.x >> 16);
        acc[2] += bf2f(z0.y & 0xffffu);
        acc[3] += bf2f(z0.y >> 16);
      }
    }
  }
#pragma unroll
  for (int i = 0; i < 4; ++i) {
    acc[i] += __shfl_xor(acc[i], 16, 64);
    acc[i] += __shfl_xor(acc[i], 32, 64);
  }
  if (slot == 0) {
    if (out_bf) {
      unsigned long long pv =
          (unsigned long long)((unsigned)f2bf(acc[0]) | ((unsigned)f2bf(acc[1]) << 16)) |
          ((unsigned long long)((unsigned)f2bf(acc[2]) | ((unsigned)f2bf(acc[3]) << 16)) << 32);
      __builtin_nontemporal_store(pv, (unsigned long long*)(out_bf + (size_t)v * DIM_H + col));
    } else {
      f32x4 fv = {acc[0], acc[1], acc[2], acc[3]};
      __builtin_nontemporal_store(fv, (f32x4*)(out_f32 + (size_t)v * DIM_H + col));
    }
  }
}

// ================= launch =================
extern "C" void kernel_launch(void* const* d_in, const int* in_sizes, int n_in,
                              void* d_out, int out_size, void* d_ws, size_t ws_size,
                              hipStream_t stream) {
  const float* feat = (const float*)d_in[0];
  const float* fc_W = (const float*)d_in[1];
  const float* fc_b = (const float*)d_in[2];
  const float* gat_W = (const float*)d_in[3];
  const float* gat_al = (const float*)d_in[4];
  const float* gat_ar = (const float*)d_in[5];
  const float* gat_b = (const float*)d_in[6];
  // d_in[7] = beta unused (reference returns Z_prev)
  const int* src = (const int*)d_in[8];
  const int* dst = (const int*)d_in[9];
  float* out = (float*)d_out;

  char* w = (char*)d_ws;
  auto alloc = [&](size_t bytes) {
    char* p = w;
    w += (bytes + 255) & ~(size_t)255;
    return p;
  };
  unsigned short* hbf   = (unsigned short*)alloc((size_t)M_PAD * DIM_H * 2);
  unsigned short* fcWt  = (unsigned short*)alloc((size_t)DIM_H * DIM_IN * 2);
  unsigned short* gatWt = (unsigned short*)alloc((size_t)NUM_GNNS * DIM_H * DIM_H * 2);
  float* el    = (float*)alloc((size_t)N_NODES * 4);
  float* er    = (float*)alloc((size_t)N_NODES * 4);
  int* counts  = (int*)alloc((size_t)2 * N_NODES * 4);   // counts+cursor contiguous
  int* cursor  = counts + N_NODES;
  int* indptr  = (int*)alloc((size_t)(N_NODES + 1) * 4);
  int* adjsrc  = (int*)alloc((size_t)N_EDGES * 4);
  char* uni = alloc((size_t)M_PAD * DIM_IN * 2);   // Abf (30.9 MB) -> alpha (1.28 MB) -> Z1 (20.6 MB)
  unsigned short* Abf = (unsigned short*)uni;      // live: convert + first GEMM only
  float* alpha = (float*)uni;                      // live: GAT layers only
  unsigned short* Z1  = (unsigned short*)uni;      // live: propagation only
  unsigned short* zbf = (unsigned short*)d_out;

  // ---- CSR build ----
  hipMemsetAsync(counts, 0, sizeof(int) * 2 * N_NODES, stream);
  count_edges<<<(N_EDGES + 255) / 256, 256, 0, stream>>>(dst, counts);
  scan_kernel<<<1, 1024, 0, stream>>>(counts, indptr);
  fill_adj<<<(N_EDGES + 255) / 256, 256, 0, stream>>>(src, dst, indptr, cursor, adjsrc);

  // ---- bf16 prep ----
  convert_feat<<<(M_PAD * DIM_IN / 8 + 255) / 256, 256, 0, stream>>>(feat, Abf);
  transpose_bf16<<<dim3(DIM_IN / 32, DIM_H / 32, 1), dim3(32, 8), 0, stream>>>(fc_W, fcWt, DIM_IN, DIM_H);
  transpose_bf16<<<dim3(DIM_H / 32, DIM_H / 32, NUM_GNNS), dim3(32, 8), 0, stream>>>(gat_W, gatWt, DIM_H, DIM_H);

  gemm_mfma_bf16<<<GEMM_GRID, 256, 0, stream>>>(Abf, fcWt, fc_b, hbf, DIM_IN);

  int nwaveblocks = (N_NODES * 64 + 255) / 256;
  for (int l = 0; l < NUM_GNNS; ++l) {
    gemm_mfma_bf16<<<GEMM_GRID, 256, 0, stream>>>(hbf, gatWt + (size_t)l * DIM_H * DIM_H,
                                                  nullptr, zbf, DIM_H);
    eler_bf<<<nwaveblocks, 256, 0, stream>>>(zbf, gat_al + (size_t)l * DIM_H,
                                             gat_ar + (size_t)l * DIM_H, el, er);
    edge_softmax_alpha<<<nwaveblocks, 256, 0, stream>>>(el, er, indptr, adjsrc, alpha);
    gat_aggregate_sliced<<<SLICED_GRID, 256, 0, stream>>>(
        zbf, alpha, indptr, adjsrc, gat_b + (size_t)l * DIM_H, hbf);
  }

  // ---- 3 propagation hops, XCD-sliced ----
  propagate_sliced<<<SLICED_GRID, 256, 0, stream>>>(hbf, indptr, adjsrc, Z1, nullptr);
  propagate_sliced<<<SLICED_GRID, 256, 0, stream>>>(Z1, indptr, adjsrc, hbf, nullptr);
  propagate_sliced<<<SLICED_GRID, 256, 0, stream>>>(hbf, indptr, adjsrc, nullptr, out);
}